// Round 4
// baseline (797.579 us; speedup 1.0000x reference)
//
#include <hip/hip_runtime.h>
#include <hip/hip_bf16.h>

// ---------------------------------------------------------------------------
// MessagePassingModel: N=10000 atoms, E=160000 edges, NC=9 SH channels,
// F=32 features, NB=16 radial basis, NITER=3.
// R3 profile: atom_kernel 67us x3, VALUBusy 9.7% -> latency-bound on
// shfl/LDS GEMV. R4: shuffle-free atom kernel (lane-per-atom GEMV, scalar
// W operands), fp32 weight/pos pre-convert, y zero-fill instead of copy.
// Input float dtype (fp32 vs bf16) sniffed at runtime (round-3 fix).
// ---------------------------------------------------------------------------

#define NITER 3

// wcvt (fp32 converted weights) layout offsets, in floats
#define OFF_WB    0        // [NITER][3][16][32] = 4608
#define OFF_W1    4608     // [NITER][3][32][32] = 9216
#define OFF_B1    13824    // [NITER][32] = 96
#define OFF_W2    13920    // 9216
#define OFF_B2    23136    // 96
#define OFF_WT00  23232    // [32][4] = 128
#define OFF_WT11  23360    // 128
#define OFF_WMONO 23488    // [4][4] = 16
#define OFF_EB    23504    // 18
#define OFF_EMB   23522    // [18][32] = 576
#define WC_TOTAL  24098

__device__ __forceinline__ float b2f(const __hip_bfloat16 v) { return __bfloat162float(v); }

// Analytic real-Gaunt coefficients for l<=2:
#define KC0 0.28209479177387814f
#define KG1 0.21850968611841584f
#define KG2 0.12615662610100802f
#define KG3 0.18022375157287861f
#define KG4 0.09011187578643931f
#define KG5 0.15607834722743988f

// --- sniff input float dtype ------------------------------------------------
__global__ void sniff_kernel(const void* __restrict__ pos, int* __restrict__ flag) {
    if (blockIdx.x == 0 && threadIdx.x == 0) {
        const __hip_bfloat16* p = (const __hip_bfloat16*)pos;
        int isf32 = 0;
        for (int k = 0; k < 64; k++) {
            float v = b2f(p[k]);
            if (!(fabsf(v) < 1.0e6f)) isf32 = 1;   // NaN also trips
        }
        *flag = isf32;
    }
}

__device__ __forceinline__ float ldany(const void* p, int i, bool f32) {
    return f32 ? ((const float*)p)[i] : b2f(((const __hip_bfloat16*)p)[i]);
}

// --- convert positions + all weights to fp32 workspace ----------------------
__global__ void convert_kernel(const void* pos, const void* Wb, const void* W1,
        const void* b1, const void* W2, const void* b2, const void* Wt00,
        const void* Wt11, const void* Wmono, const void* eb, const void* emb,
        float* __restrict__ posf, float* __restrict__ wc, int N,
        const int* __restrict__ flag) {
    int i = blockIdx.x * blockDim.x + threadIdx.x;
    bool f32 = (*flag) != 0;
    int np = N * 3;
    if (i < np) { posf[i] = ldany(pos, i, f32); return; }
    int j = i - np;
    if (j >= WC_TOTAL) return;
    const void* src; int rel;
    if      (j < OFF_W1)    { src = Wb;    rel = j; }
    else if (j < OFF_B1)    { src = W1;    rel = j - OFF_W1; }
    else if (j < OFF_W2)    { src = b1;    rel = j - OFF_B1; }
    else if (j < OFF_B2)    { src = W2;    rel = j - OFF_W2; }
    else if (j < OFF_WT00)  { src = b2;    rel = j - OFF_B2; }
    else if (j < OFF_WT11)  { src = Wt00;  rel = j - OFF_WT00; }
    else if (j < OFF_WMONO) { src = Wt11;  rel = j - OFF_WT11; }
    else if (j < OFF_EB)    { src = Wmono; rel = j - OFF_WMONO; }
    else if (j < OFF_EMB)   { src = eb;    rel = j - OFF_EB; }
    else                    { src = emb;   rel = j - OFF_EMB; }
    wc[j] = ldany(src, rel, f32);
}

// --- x[:,0,:] = embed[an], rest 0 -------------------------------------------
__global__ void init_x_kernel(const int* __restrict__ an, const float* __restrict__ wc,
                              float* __restrict__ x, int N) {
    int idx = blockIdx.x * blockDim.x + threadIdx.x;
    if (idx >= N * 288) return;
    int n = idx / 288, rem = idx % 288;
    float val = 0.0f;
    if (rem < 32) val = wc[OFF_EMB + an[n] * 32 + rem];
    x[idx] = val;
}

// --- y = 0 ------------------------------------------------------------------
__global__ void zero_kernel(float4* __restrict__ b, int n) {
    int i = blockIdx.x * blockDim.x + threadIdx.x;
    int stride = gridDim.x * blockDim.x;
    float4 z = make_float4(0.f, 0.f, 0.f, 0.f);
    for (; i < n; i += stride) b[i] = z;
}

// --- edge message + scatter-add (half-wave of 32 lanes = F per edge) --------
__global__ __launch_bounds__(256) void edge_kernel(
        const float* __restrict__ x, float* __restrict__ y,
        const float* __restrict__ posf,
        const int* __restrict__ srcI, const int* __restrict__ dstI,
        const float* __restrict__ Wbi, int E) {
    int f  = threadIdx.x & 31;
    int hw = (blockIdx.x * blockDim.x + threadIdx.x) >> 5;
    int nhw = gridDim.x * (blockDim.x >> 5);
    float w0[16], w1[16], w2[16];
    #pragma unroll
    for (int n = 0; n < 16; n++) {
        w0[n] = Wbi[(0*16 + n)*32 + f];
        w1[n] = Wbi[(1*16 + n)*32 + f];
        w2[n] = Wbi[(2*16 + n)*32 + f];
    }
    const float BIN[16] = {1.f,15.f,105.f,455.f,1365.f,3003.f,5005.f,6435.f,
                           6435.f,5005.f,3003.f,1365.f,455.f,105.f,15.f,1.f};
    for (int e = hw; e < E; e += nhw) {
        int s = srcI[e], d = dstI[e];
        float dx = posf[s*3+0] - posf[d*3+0];
        float dy = posf[s*3+1] - posf[d*3+1];
        float dz = posf[s*3+2] - posf[d*3+2];
        float r2 = dx*dx + dy*dy + dz*dz + 1e-12f;
        if (r2 >= 16.0f) continue;           // fc = 0, no message
        float r  = sqrtf(r2);
        float t2 = r2 * 0.0625f;
        float fc = __expf(-t2 / (1.0f - t2));
        float u = 1.0f / (1.0f + r);
        float v = 1.0f - u;
        float up = 1.0f;
        float vp[16];
        vp[0] = 1.0f;
        #pragma unroll
        for (int k = 1; k < 16; k++) vp[k] = vp[k-1] * v;
        float rw0 = 0.f, rw1 = 0.f, rw2 = 0.f;
        #pragma unroll
        for (int n = 0; n < 16; n++) {
            float rn = BIN[n] * up * vp[15-n] * fc;
            up *= u;
            rw0 = fmaf(rn, w0[n], rw0);
            rw1 = fmaf(rn, w1[n], rw1);
            rw2 = fmaf(rn, w2[n], rw2);
        }
        float ir = 1.0f / r;
        float ux = dx*ir, uy = dy*ir, uz = dz*ir;
        const float c0 = 0.28209479177387814f, c1 = 0.4886025119029199f;
        const float c2a = 1.0925484305920792f, c2b = 0.31539156525252005f, c2c = 0.5462742152960396f;
        float B0 = c0*rw0;
        float B1 = c1*uy*rw1, B2 = c1*uz*rw1, B3 = c1*ux*rw1;
        float B4 = c2a*ux*uy*rw2, B5 = c2a*uy*uz*rw2;
        float B6 = c2b*(3.0f*uz*uz - 1.0f)*rw2;
        float B7 = c2a*ux*uz*rw2, B8 = c2c*(ux*ux - uy*uy)*rw2;
        const float* xp = x + s*288 + f;
        float X0 = xp[0],   X1 = xp[32],  X2 = xp[64],  X3 = xp[96],  X4 = xp[128];
        float X5 = xp[160], X6 = xp[192], X7 = xp[224], X8 = xp[256];
        float* yp = y + d*288 + f;
        float m;
        m = KC0*(X0*B0 + X1*B1 + X2*B2 + X3*B3 + X4*B4 + X5*B5 + X6*B6 + X7*B7 + X8*B8);
        unsafeAtomicAdd(yp + 0, m);
        m = KC0*(X0*B1 + X1*B0) + KG1*(X3*B4 + X4*B3 + X2*B5 + X5*B2)
          - KG2*(X1*B6 + X6*B1) - KG1*(X1*B8 + X8*B1);
        unsafeAtomicAdd(yp + 32, m);
        m = KC0*(X0*B2 + X2*B0) + KG1*(X1*B5 + X5*B1 + X3*B7 + X7*B3)
          + 2.0f*KG2*(X2*B6 + X6*B2);
        unsafeAtomicAdd(yp + 64, m);
        m = KC0*(X0*B3 + X3*B0) + KG1*(X1*B4 + X4*B1 + X2*B7 + X7*B2)
          - KG2*(X3*B6 + X6*B3) + KG1*(X3*B8 + X8*B3);
        unsafeAtomicAdd(yp + 96, m);
        m = KC0*(X0*B4 + X4*B0) + KG1*(X1*B3 + X3*B1) + KG5*(X5*B7 + X7*B5)
          - KG3*(X4*B6 + X6*B4);
        unsafeAtomicAdd(yp + 128, m);
        m = KC0*(X0*B5 + X5*B0) + KG1*(X1*B2 + X2*B1) + KG5*(X4*B7 + X7*B4)
          + KG4*(X5*B6 + X6*B5) - KG5*(X5*B8 + X8*B5);
        unsafeAtomicAdd(yp + 160, m);
        m = KC0*(X0*B6 + X6*B0) - KG2*X1*B1 + 2.0f*KG2*X2*B2 - KG2*X3*B3
          - KG3*X4*B4 + KG4*X5*B5 + KG3*X6*B6 + KG4*X7*B7 - KG3*X8*B8;
        unsafeAtomicAdd(yp + 192, m);
        m = KC0*(X0*B7 + X7*B0) + KG1*(X2*B3 + X3*B2) + KG5*(X4*B5 + X5*B4)
          + KG4*(X6*B7 + X7*B6) + KG5*(X7*B8 + X8*B7);
        unsafeAtomicAdd(yp + 224, m);
        m = KC0*(X0*B8 + X8*B0) - KG1*X1*B1 + KG1*X3*B3 - KG5*X5*B5 + KG5*X7*B7
          - KG3*(X6*B8 + X8*B6);
        unsafeAtomicAdd(yp + 256, m);
    }
}

// --- atom update: x += dense2(silu(dense1(x + msg))) ------------------------
// One wave = 64 atoms x 1 channel. Each LANE computes the full 32-wide GEMV
// chain for its atom; W/b are wave-uniform -> scalar (SGPR) operands, no
// LDS, no shuffles. 2048 unrolled FMAs per lane.
__global__ __launch_bounds__(256) void atom_kernel(
        float* __restrict__ x, const float* __restrict__ ymsg,
        const float* __restrict__ W1i, const float* __restrict__ b1i,
        const float* __restrict__ W2i, const float* __restrict__ b2i,
        int N, int nwaves) {
    int w = blockIdx.x * 4 + (threadIdx.x >> 6);
    if (w >= nwaves) return;
    int lane = threadIdx.x & 63;
    int c    = w % 9;
    int ablk = w / 9;
    int atom = ablk * 64 + lane;
    bool act = atom < N;
    int d = (c == 0) ? 0 : ((c < 4) ? 1 : 2);
    const float* W1 = W1i + d * 1024;
    const float* W2 = W2i + d * 1024;
    const float* xb = x + (size_t)atom * 288 + c * 32;
    const float* yb = ymsg + (size_t)atom * 288 + c * 32;
    float xr[32], in[32];
    #pragma unroll
    for (int k = 0; k < 8; k++) {
        float4 xv = act ? *(const float4*)(xb + 4*k) : make_float4(0,0,0,0);
        float4 yv = act ? *(const float4*)(yb + 4*k) : make_float4(0,0,0,0);
        xr[4*k+0] = xv.x; xr[4*k+1] = xv.y; xr[4*k+2] = xv.z; xr[4*k+3] = xv.w;
        in[4*k+0] = xv.x + yv.x; in[4*k+1] = xv.y + yv.y;
        in[4*k+2] = xv.z + yv.z; in[4*k+3] = xv.w + yv.w;
    }
    float acc[32];
    #pragma unroll
    for (int g = 0; g < 32; g++) acc[g] = (c == 0) ? b1i[g] : 0.0f;
    #pragma unroll
    for (int f = 0; f < 32; f++) {
        float xf = in[f];
        #pragma unroll
        for (int g = 0; g < 32; g++) acc[g] = fmaf(xf, W1[f*32 + g], acc[g]);
    }
    #pragma unroll
    for (int g = 0; g < 32; g++) {
        float a = acc[g];
        acc[g] = a * __builtin_amdgcn_rcpf(1.0f + __expf(-a));   // silu
    }
    #pragma unroll
    for (int g = 0; g < 32; g++) in[g] = (c == 0) ? b2i[g] : 0.0f;
    #pragma unroll
    for (int f = 0; f < 32; f++) {
        float sf = acc[f];
        #pragma unroll
        for (int g = 0; g < 32; g++) in[g] = fmaf(sf, W2[f*32 + g], in[g]);
    }
    float* xw = x + (size_t)atom * 288 + c * 32;
    if (act) {
        #pragma unroll
        for (int k = 0; k < 8; k++) {
            *(float4*)(xw + 4*k) = make_float4(xr[4*k+0] + in[4*k+0],
                                               xr[4*k+1] + in[4*k+1],
                                               xr[4*k+2] + in[4*k+2],
                                               xr[4*k+3] + in[4*k+3]);
        }
    }
}

// --- readout (mono, dip) ----------------------------------------------------
__global__ void readout_kernel(const float* __restrict__ x,
        const int* __restrict__ an, const float* __restrict__ posf,
        const float* __restrict__ wc, void* __restrict__ out, int N,
        const int* __restrict__ flag) {
    int n = blockIdx.x * blockDim.x + threadIdx.x;
    if (n >= N) return;
    bool f32 = (*flag) != 0;
    const float* Wt00  = wc + OFF_WT00;
    const float* Wt11  = wc + OFF_WT11;
    const float* Wmono = wc + OFF_WMONO;
    const float* xb = x + (size_t)n * 288;
    float q[4] = {0.f, 0.f, 0.f, 0.f};
    for (int f = 0; f < 32; f++) {
        float xv = xb[f];
        #pragma unroll
        for (int j = 0; j < 4; j++) q[j] = fmaf(xv, Wt00[f*4 + j], q[j]);
    }
    float ebv = wc[OFF_EB + an[n]];
    #pragma unroll
    for (int m = 0; m < 4; m++) {
        float acc = ebv;
        #pragma unroll
        for (int j = 0; j < 4; j++) acc = fmaf(q[j], Wmono[j*4 + m], acc);
        if (f32) ((float*)out)[n*4 + m] = acc;
        else ((__hip_bfloat16*)out)[n*4 + m] = __float2bfloat16(acc);
    }
    #pragma unroll
    for (int c = 0; c < 3; c++) {
        float pc = posf[n*3 + c];
        const float* xc = xb + (1 + c)*32;
        float dq[4] = {0.f, 0.f, 0.f, 0.f};
        for (int f = 0; f < 32; f++) {
            float xv = xc[f];
            #pragma unroll
            for (int m = 0; m < 4; m++) dq[m] = fmaf(xv, Wt11[f*4 + m], dq[m]);
        }
        #pragma unroll
        for (int m = 0; m < 4; m++) {
            float v = dq[m];
            v = v * __builtin_amdgcn_rcpf(1.0f + __expf(-v));   // silu
            v = fminf(fmaxf(v, -0.3f), 0.3f);                   // clip
            v += pc;
            if (f32) ((float*)out)[N*4 + n*12 + c*4 + m] = v;
            else ((__hip_bfloat16*)out)[N*4 + n*12 + c*4 + m] = __float2bfloat16(v);
        }
    }
}

extern "C" void kernel_launch(void* const* d_in, const int* in_sizes, int n_in,
                              void* d_out, int out_size, void* d_ws, size_t ws_size,
                              hipStream_t stream) {
    const int* an    = (const int*)d_in[0];
    const void* pos  = d_in[1];
    const int* dstI  = (const int*)d_in[2];
    const int* srcI  = (const int*)d_in[3];
    const void* embed= d_in[4];
    const void* Wb   = d_in[5];
    const void* W1   = d_in[6];
    const void* b1   = d_in[7];
    const void* W2   = d_in[8];
    const void* b2   = d_in[9];
    const void* Wt00 = d_in[10];
    const void* Wt11 = d_in[11];
    const void* Wmono= d_in[12];
    const void* eb   = d_in[13];
    int N = in_sizes[0];
    int E = in_sizes[2];

    // ws layout: flag(16B) | x (N*288 f32) | y (N*288) | posf (N*3) | wcvt
    int* flag   = (int*)d_ws;
    float* x    = (float*)((char*)d_ws + 16);
    float* y    = x + (size_t)N * 288;
    float* posf = y + (size_t)N * 288;
    float* wc   = posf + (size_t)N * 3;

    sniff_kernel<<<1, 64, 0, stream>>>(pos, flag);
    {
        int tot = N * 3 + WC_TOTAL;
        convert_kernel<<<(tot + 255)/256, 256, 0, stream>>>(
            pos, Wb, W1, b1, W2, b2, Wt00, Wt11, Wmono, eb, embed,
            posf, wc, N, flag);
    }
    init_x_kernel<<<(N*288 + 255)/256, 256, 0, stream>>>(an, wc, x, N);

    int nablk  = (N + 63) / 64;
    int nwaves = nablk * 9;
    int ablocks = (nwaves + 3) / 4;
    for (int i = 0; i < NITER; i++) {
        zero_kernel<<<512, 256, 0, stream>>>((float4*)y, N * 72);
        edge_kernel<<<2048, 256, 0, stream>>>(x, y, posf, srcI, dstI,
                                              wc + OFF_WB + (size_t)i*1536, E);
        atom_kernel<<<ablocks, 256, 0, stream>>>(x, y,
            wc + OFF_W1 + (size_t)i*3072, wc + OFF_B1 + (size_t)i*32,
            wc + OFF_W2 + (size_t)i*3072, wc + OFF_B2 + (size_t)i*32,
            N, nwaves);
    }
    readout_kernel<<<(N + 255)/256, 256, 0, stream>>>(x, an, posf, wc, d_out, N, flag);
}

// Round 5
// 390.703 us; speedup vs baseline: 2.0414x; 2.0414x over previous
//
#include <hip/hip_runtime.h>
#include <hip/hip_bf16.h>

// ---------------------------------------------------------------------------
// MessagePassingModel: N=10000 atoms, E=160000 edges, NC=9 SH channels,
// F=32 features, NB=16 radial basis, NITER=3.
// R4 post-mortem: lane-per-atom GEMV uncoalesced (1152B stride) -> 388 MB
// HBM traffic/dispatch, 216us. R5: back to R3 half-wave atom kernel
// (coalesced 128B rows, shfl broadcast, W in LDS) with FULL grid
// (1250 blocks, was 512 -> grid-limited 17% occupancy) + fp32 preconverted
// weights + __expf. Edge kernel unchanged from R4 (need its counters).
// ---------------------------------------------------------------------------

#define NITER 3

// wcvt (fp32 converted weights) layout offsets, in floats
#define OFF_WB    0        // [NITER][3][16][32] = 4608
#define OFF_W1    4608     // [NITER][3][32][32] = 9216
#define OFF_B1    13824    // [NITER][32] = 96
#define OFF_W2    13920    // 9216
#define OFF_B2    23136    // 96
#define OFF_WT00  23232    // [32][4] = 128
#define OFF_WT11  23360    // 128
#define OFF_WMONO 23488    // [4][4] = 16
#define OFF_EB    23504    // 18
#define OFF_EMB   23522    // [18][32] = 576
#define WC_TOTAL  24098

__device__ __forceinline__ float b2f(const __hip_bfloat16 v) { return __bfloat162float(v); }

// Analytic real-Gaunt coefficients for l<=2:
#define KC0 0.28209479177387814f
#define KG1 0.21850968611841584f
#define KG2 0.12615662610100802f
#define KG3 0.18022375157287861f
#define KG4 0.09011187578643931f
#define KG5 0.15607834722743988f

// --- sniff input float dtype ------------------------------------------------
__global__ void sniff_kernel(const void* __restrict__ pos, int* __restrict__ flag) {
    if (blockIdx.x == 0 && threadIdx.x == 0) {
        const __hip_bfloat16* p = (const __hip_bfloat16*)pos;
        int isf32 = 0;
        for (int k = 0; k < 64; k++) {
            float v = b2f(p[k]);
            if (!(fabsf(v) < 1.0e6f)) isf32 = 1;   // NaN also trips
        }
        *flag = isf32;
    }
}

__device__ __forceinline__ float ldany(const void* p, int i, bool f32) {
    return f32 ? ((const float*)p)[i] : b2f(((const __hip_bfloat16*)p)[i]);
}

// --- convert positions + all weights to fp32 workspace ----------------------
__global__ void convert_kernel(const void* pos, const void* Wb, const void* W1,
        const void* b1, const void* W2, const void* b2, const void* Wt00,
        const void* Wt11, const void* Wmono, const void* eb, const void* emb,
        float* __restrict__ posf, float* __restrict__ wc, int N,
        const int* __restrict__ flag) {
    int i = blockIdx.x * blockDim.x + threadIdx.x;
    bool f32 = (*flag) != 0;
    int np = N * 3;
    if (i < np) { posf[i] = ldany(pos, i, f32); return; }
    int j = i - np;
    if (j >= WC_TOTAL) return;
    const void* src; int rel;
    if      (j < OFF_W1)    { src = Wb;    rel = j; }
    else if (j < OFF_B1)    { src = W1;    rel = j - OFF_W1; }
    else if (j < OFF_W2)    { src = b1;    rel = j - OFF_B1; }
    else if (j < OFF_B2)    { src = W2;    rel = j - OFF_W2; }
    else if (j < OFF_WT00)  { src = b2;    rel = j - OFF_B2; }
    else if (j < OFF_WT11)  { src = Wt00;  rel = j - OFF_WT00; }
    else if (j < OFF_WMONO) { src = Wt11;  rel = j - OFF_WT11; }
    else if (j < OFF_EB)    { src = Wmono; rel = j - OFF_WMONO; }
    else if (j < OFF_EMB)   { src = eb;    rel = j - OFF_EB; }
    else                    { src = emb;   rel = j - OFF_EMB; }
    wc[j] = ldany(src, rel, f32);
}

// --- x[:,0,:] = embed[an], rest 0 -------------------------------------------
__global__ void init_x_kernel(const int* __restrict__ an, const float* __restrict__ wc,
                              float* __restrict__ x, int N) {
    int idx = blockIdx.x * blockDim.x + threadIdx.x;
    if (idx >= N * 288) return;
    int n = idx / 288, rem = idx % 288;
    float val = 0.0f;
    if (rem < 32) val = wc[OFF_EMB + an[n] * 32 + rem];
    x[idx] = val;
}

// --- y = x ------------------------------------------------------------------
__global__ void copy_kernel(const float4* __restrict__ a, float4* __restrict__ b, int n) {
    int i = blockIdx.x * blockDim.x + threadIdx.x;
    int stride = gridDim.x * blockDim.x;
    for (; i < n; i += stride) b[i] = a[i];
}

// --- edge message + scatter-add (half-wave of 32 lanes = F per edge) --------
__global__ __launch_bounds__(256) void edge_kernel(
        const float* __restrict__ x, float* __restrict__ y,
        const float* __restrict__ posf,
        const int* __restrict__ srcI, const int* __restrict__ dstI,
        const float* __restrict__ Wbi, int E) {
    int f  = threadIdx.x & 31;
    int hw = (blockIdx.x * blockDim.x + threadIdx.x) >> 5;
    int nhw = gridDim.x * (blockDim.x >> 5);
    float w0[16], w1[16], w2[16];
    #pragma unroll
    for (int n = 0; n < 16; n++) {
        w0[n] = Wbi[(0*16 + n)*32 + f];
        w1[n] = Wbi[(1*16 + n)*32 + f];
        w2[n] = Wbi[(2*16 + n)*32 + f];
    }
    const float BIN[16] = {1.f,15.f,105.f,455.f,1365.f,3003.f,5005.f,6435.f,
                           6435.f,5005.f,3003.f,1365.f,455.f,105.f,15.f,1.f};
    for (int e = hw; e < E; e += nhw) {
        int s = srcI[e], d = dstI[e];
        float dx = posf[s*3+0] - posf[d*3+0];
        float dy = posf[s*3+1] - posf[d*3+1];
        float dz = posf[s*3+2] - posf[d*3+2];
        float r2 = dx*dx + dy*dy + dz*dz + 1e-12f;
        if (r2 >= 16.0f) continue;           // fc = 0, no message
        float r  = sqrtf(r2);
        float t2 = r2 * 0.0625f;
        float fc = __expf(-t2 / (1.0f - t2));
        float u = 1.0f / (1.0f + r);
        float v = 1.0f - u;
        float up = 1.0f;
        float vp[16];
        vp[0] = 1.0f;
        #pragma unroll
        for (int k = 1; k < 16; k++) vp[k] = vp[k-1] * v;
        float rw0 = 0.f, rw1 = 0.f, rw2 = 0.f;
        #pragma unroll
        for (int n = 0; n < 16; n++) {
            float rn = BIN[n] * up * vp[15-n] * fc;
            up *= u;
            rw0 = fmaf(rn, w0[n], rw0);
            rw1 = fmaf(rn, w1[n], rw1);
            rw2 = fmaf(rn, w2[n], rw2);
        }
        float ir = 1.0f / r;
        float ux = dx*ir, uy = dy*ir, uz = dz*ir;
        const float c0 = 0.28209479177387814f, c1 = 0.4886025119029199f;
        const float c2a = 1.0925484305920792f, c2b = 0.31539156525252005f, c2c = 0.5462742152960396f;
        float B0 = c0*rw0;
        float B1 = c1*uy*rw1, B2 = c1*uz*rw1, B3 = c1*ux*rw1;
        float B4 = c2a*ux*uy*rw2, B5 = c2a*uy*uz*rw2;
        float B6 = c2b*(3.0f*uz*uz - 1.0f)*rw2;
        float B7 = c2a*ux*uz*rw2, B8 = c2c*(ux*ux - uy*uy)*rw2;
        const float* xp = x + s*288 + f;
        float X0 = xp[0],   X1 = xp[32],  X2 = xp[64],  X3 = xp[96],  X4 = xp[128];
        float X5 = xp[160], X6 = xp[192], X7 = xp[224], X8 = xp[256];
        float* yp = y + d*288 + f;
        float m;
        m = KC0*(X0*B0 + X1*B1 + X2*B2 + X3*B3 + X4*B4 + X5*B5 + X6*B6 + X7*B7 + X8*B8);
        unsafeAtomicAdd(yp + 0, m);
        m = KC0*(X0*B1 + X1*B0) + KG1*(X3*B4 + X4*B3 + X2*B5 + X5*B2)
          - KG2*(X1*B6 + X6*B1) - KG1*(X1*B8 + X8*B1);
        unsafeAtomicAdd(yp + 32, m);
        m = KC0*(X0*B2 + X2*B0) + KG1*(X1*B5 + X5*B1 + X3*B7 + X7*B3)
          + 2.0f*KG2*(X2*B6 + X6*B2);
        unsafeAtomicAdd(yp + 64, m);
        m = KC0*(X0*B3 + X3*B0) + KG1*(X1*B4 + X4*B1 + X2*B7 + X7*B2)
          - KG2*(X3*B6 + X6*B3) + KG1*(X3*B8 + X8*B3);
        unsafeAtomicAdd(yp + 96, m);
        m = KC0*(X0*B4 + X4*B0) + KG1*(X1*B3 + X3*B1) + KG5*(X5*B7 + X7*B5)
          - KG3*(X4*B6 + X6*B4);
        unsafeAtomicAdd(yp + 128, m);
        m = KC0*(X0*B5 + X5*B0) + KG1*(X1*B2 + X2*B1) + KG5*(X4*B7 + X7*B4)
          + KG4*(X5*B6 + X6*B5) - KG5*(X5*B8 + X8*B5);
        unsafeAtomicAdd(yp + 160, m);
        m = KC0*(X0*B6 + X6*B0) - KG2*X1*B1 + 2.0f*KG2*X2*B2 - KG2*X3*B3
          - KG3*X4*B4 + KG4*X5*B5 + KG3*X6*B6 + KG4*X7*B7 - KG3*X8*B8;
        unsafeAtomicAdd(yp + 192, m);
        m = KC0*(X0*B7 + X7*B0) + KG1*(X2*B3 + X3*B2) + KG5*(X4*B5 + X5*B4)
          + KG4*(X6*B7 + X7*B6) + KG5*(X7*B8 + X8*B7);
        unsafeAtomicAdd(yp + 224, m);
        m = KC0*(X0*B8 + X8*B0) - KG1*X1*B1 + KG1*X3*B3 - KG5*X5*B5 + KG5*X7*B7
          - KG3*(X6*B8 + X8*B6);
        unsafeAtomicAdd(yp + 256, m);
    }
}

// --- atom update: x += dense2(silu(dense1(y))) ------------------------------
// Half-wave of 32 lanes = one atom; lane = output feature g. y-row reads and
// x-row writes are coalesced 128B. in[f] broadcast via __shfl, W from LDS
// (stride-1, conflict-free). Grid covers all atoms (R3 was grid-limited).
__global__ __launch_bounds__(256) void atom_kernel(
        float* __restrict__ x, const float* __restrict__ y,
        const float* __restrict__ W1i, const float* __restrict__ b1i,
        const float* __restrict__ W2i, const float* __restrict__ b2i,
        int N) {
    __shared__ float W1s[3*32*32];
    __shared__ float W2s[3*32*32];
    __shared__ float b1s[32], b2s[32];
    for (int idx = threadIdx.x; idx < 3072; idx += 256) {
        W1s[idx] = W1i[idx];
        W2s[idx] = W2i[idx];
    }
    if (threadIdx.x < 32) {
        b1s[threadIdx.x] = b1i[threadIdx.x];
        b2s[threadIdx.x] = b2i[threadIdx.x];
    }
    __syncthreads();
    int g = threadIdx.x & 31;
    int n = (blockIdx.x * blockDim.x + threadIdx.x) >> 5;   // atom index
    if (n >= N) return;
    const int DEGc[9] = {0,1,1,1,2,2,2,2,2};
    const float* yb = y + (size_t)n * 288;
    float yv[9], sv[9];
    #pragma unroll
    for (int c = 0; c < 9; c++) yv[c] = yb[c*32 + g];
    #pragma unroll
    for (int c = 0; c < 9; c++) {
        const float* Wcol = W1s + DEGc[c]*1024;
        float acc = (c == 0) ? b1s[g] : 0.0f;
        #pragma unroll
        for (int fi = 0; fi < 32; fi++)
            acc = fmaf(__shfl(yv[c], fi, 32), Wcol[fi*32 + g], acc);
        sv[c] = acc * __builtin_amdgcn_rcpf(1.0f + __expf(-acc));   // silu
    }
    float* xb = x + (size_t)n * 288;
    #pragma unroll
    for (int c = 0; c < 9; c++) {
        const float* Wcol = W2s + DEGc[c]*1024;
        float acc = (c == 0) ? b2s[g] : 0.0f;
        #pragma unroll
        for (int fi = 0; fi < 32; fi++)
            acc = fmaf(__shfl(sv[c], fi, 32), Wcol[fi*32 + g], acc);
        xb[c*32 + g] += acc;
    }
}

// --- readout (mono, dip) ----------------------------------------------------
__global__ void readout_kernel(const float* __restrict__ x,
        const int* __restrict__ an, const float* __restrict__ posf,
        const float* __restrict__ wc, void* __restrict__ out, int N,
        const int* __restrict__ flag) {
    int n = blockIdx.x * blockDim.x + threadIdx.x;
    if (n >= N) return;
    bool f32 = (*flag) != 0;
    const float* Wt00  = wc + OFF_WT00;
    const float* Wt11  = wc + OFF_WT11;
    const float* Wmono = wc + OFF_WMONO;
    const float* xb = x + (size_t)n * 288;
    float q[4] = {0.f, 0.f, 0.f, 0.f};
    for (int f = 0; f < 32; f++) {
        float xv = xb[f];
        #pragma unroll
        for (int j = 0; j < 4; j++) q[j] = fmaf(xv, Wt00[f*4 + j], q[j]);
    }
    float ebv = wc[OFF_EB + an[n]];
    #pragma unroll
    for (int m = 0; m < 4; m++) {
        float acc = ebv;
        #pragma unroll
        for (int j = 0; j < 4; j++) acc = fmaf(q[j], Wmono[j*4 + m], acc);
        if (f32) ((float*)out)[n*4 + m] = acc;
        else ((__hip_bfloat16*)out)[n*4 + m] = __float2bfloat16(acc);
    }
    #pragma unroll
    for (int c = 0; c < 3; c++) {
        float pc = posf[n*3 + c];
        const float* xc = xb + (1 + c)*32;
        float dq[4] = {0.f, 0.f, 0.f, 0.f};
        for (int f = 0; f < 32; f++) {
            float xv = xc[f];
            #pragma unroll
            for (int m = 0; m < 4; m++) dq[m] = fmaf(xv, Wt11[f*4 + m], dq[m]);
        }
        #pragma unroll
        for (int m = 0; m < 4; m++) {
            float v = dq[m];
            v = v * __builtin_amdgcn_rcpf(1.0f + __expf(-v));   // silu
            v = fminf(fmaxf(v, -0.3f), 0.3f);                   // clip
            v += pc;
            if (f32) ((float*)out)[N*4 + n*12 + c*4 + m] = v;
            else ((__hip_bfloat16*)out)[N*4 + n*12 + c*4 + m] = __float2bfloat16(v);
        }
    }
}

extern "C" void kernel_launch(void* const* d_in, const int* in_sizes, int n_in,
                              void* d_out, int out_size, void* d_ws, size_t ws_size,
                              hipStream_t stream) {
    const int* an    = (const int*)d_in[0];
    const void* pos  = d_in[1];
    const int* dstI  = (const int*)d_in[2];
    const int* srcI  = (const int*)d_in[3];
    const void* embed= d_in[4];
    const void* Wb   = d_in[5];
    const void* W1   = d_in[6];
    const void* b1   = d_in[7];
    const void* W2   = d_in[8];
    const void* b2   = d_in[9];
    const void* Wt00 = d_in[10];
    const void* Wt11 = d_in[11];
    const void* Wmono= d_in[12];
    const void* eb   = d_in[13];
    int N = in_sizes[0];
    int E = in_sizes[2];

    // ws layout: flag(16B) | x (N*288 f32) | y (N*288) | posf (N*3) | wcvt
    int* flag   = (int*)d_ws;
    float* x    = (float*)((char*)d_ws + 16);
    float* y    = x + (size_t)N * 288;
    float* posf = y + (size_t)N * 288;
    float* wc   = posf + (size_t)N * 3;

    sniff_kernel<<<1, 64, 0, stream>>>(pos, flag);
    {
        int tot = N * 3 + WC_TOTAL;
        convert_kernel<<<(tot + 255)/256, 256, 0, stream>>>(
            pos, Wb, W1, b1, W2, b2, Wt00, Wt11, Wmono, eb, embed,
            posf, wc, N, flag);
    }
    init_x_kernel<<<(N*288 + 255)/256, 256, 0, stream>>>(an, wc, x, N);

    int ablocks = (N + 7) / 8;   // 8 atoms (half-waves) per 256-thread block
    for (int i = 0; i < NITER; i++) {
        copy_kernel<<<512, 256, 0, stream>>>((const float4*)x, (float4*)y, N*72);
        edge_kernel<<<2048, 256, 0, stream>>>(x, y, posf, srcI, dstI,
                                              wc + OFF_WB + (size_t)i*1536, E);
        atom_kernel<<<ablocks, 256, 0, stream>>>(x, y,
            wc + OFF_W1 + (size_t)i*3072, wc + OFF_B1 + (size_t)i*32,
            wc + OFF_W2 + (size_t)i*3072, wc + OFF_B2 + (size_t)i*32, N);
    }
    readout_kernel<<<(N + 255)/256, 256, 0, stream>>>(x, an, posf, wc, d_out, N, flag);
}